// Round 7
// baseline (229.505 us; speedup 1.0000x reference)
//
#include <hip/hip_runtime.h>
#include <hip/hip_bf16.h>

// out[u, d] = sum_k user_matrix[u, k] * features[user_graph[u, k], d]
// U = 1,000,000, K = 10, D = 32.
//
// Round 7: best-variant lock-in. Direct f32 gather (no convert pass — i8's
// gather gain was eaten by its convert cost). Two users per thread:
//   - their 80 B of indices / weights load as 5+5 dwordx4 (16B-aligned,
//     u0 even) instead of 40 scalar loads -> 4x fewer stream vmem instrs
//   - 20 independent row-gathers in flight per thread (2x MLP)
// Mapping: 8 lanes per user-pair slot; lane r owns float4 columns [4r,4r+4);
// each row gather = 8 lanes x 16 B = one aligned 128 B line.
// Model: dur ~= (graph+w)/6.3TBps + write/6.3 + fill/3.2TBps ~= 210 us.

#define U_COUNT 1000000
#define K_NBR   10
#define D_DIM   32

typedef int   i32x4 __attribute__((ext_vector_type(4)));
typedef float f32x4 __attribute__((ext_vector_type(4)));

__global__ __launch_bounds__(256) void gather_f32_pair_kernel(
    const float* __restrict__ features,   // [U, 32] f32 (reused -> cache)
    const int*   __restrict__ user_graph, // [U, 10] i32 (streamed)
    const float* __restrict__ user_matrix,// [U, 10] f32 (streamed)
    float* __restrict__ out)              // [U, 32] f32 (streamed)
{
    int t = blockIdx.x * blockDim.x + threadIdx.x;   // 4M threads
    int p = t >> 3;            // user-pair id, 500K pairs
    int r = t & 7;             // float4 slot within the 32-float row
    if (p >= U_COUNT / 2) return;
    const long long u0 = (long long)p * 2;

    // 80 B of indices + 80 B of weights for users {u0, u0+1}: 5+5 dwordx4.
    const i32x4* gp = reinterpret_cast<const i32x4*>(user_graph + u0 * K_NBR);
    const f32x4* wp = reinterpret_cast<const f32x4*>(user_matrix + u0 * K_NBR);
    i32x4 g[5];
    f32x4 w[5];
#pragma unroll
    for (int j = 0; j < 5; ++j) {
        g[j] = __builtin_nontemporal_load(gp + j);
        w[j] = __builtin_nontemporal_load(wp + j);
    }

    f32x4 acc0 = (f32x4)(0.f);
    f32x4 acc1 = (f32x4)(0.f);
#pragma unroll
    for (int k = 0; k < 2 * K_NBR; ++k) {      // fully unrolled; k>>2, k&3 static
        int   idx = g[k >> 2][k & 3];
        float wt  = w[k >> 2][k & 3];
        const f32x4* row = reinterpret_cast<const f32x4*>(
            features + (long long)idx * D_DIM);
        f32x4 v = row[r];                      // 16 B/lane, 128 B/row gather
        if (k < K_NBR) acc0 += wt * v;
        else           acc1 += wt * v;
    }

    f32x4* op = reinterpret_cast<f32x4*>(out) + (u0 * 8 + r);
    __builtin_nontemporal_store(acc0, op);      // user u0
    __builtin_nontemporal_store(acc1, op + 8);  // user u0+1
}

extern "C" void kernel_launch(void* const* d_in, const int* in_sizes, int n_in,
                              void* d_out, int out_size, void* d_ws, size_t ws_size,
                              hipStream_t stream) {
    const float* features    = (const float*)d_in[0];  // 32M f32
    const int*   user_graph  = (const int*)d_in[1];    // 10M i32
    const float* user_matrix = (const float*)d_in[2];  // 10M f32
    float*       out         = (float*)d_out;          // 32M f32

    const int block = 256;
    const int total_threads = (U_COUNT / 2) * 8;        // 4,000,000
    const int grid  = (total_threads + block - 1) / block;  // 15625

    gather_f32_pair_kernel<<<grid, block, 0, stream>>>(
        features, user_graph, user_matrix, out);
}

// Round 8
// 214.551 us; speedup vs baseline: 1.0697x; 1.0697x over previous
//
#include <hip/hip_runtime.h>
#include <hip/hip_bf16.h>

// out[u, d] = sum_k user_matrix[u, k] * features[user_graph[u, k], d]
// U = 1,000,000, K = 10, D = 32.
//
// Final structure (round-4 revert — best measured, 213 us):
//   - 8 lanes per user; lane r owns float4 columns [4r, 4r+4).
//     Each feature-row gather = 8 lanes x 16 B = one aligned 128 B line.
//   - Direct f32 gather: minimum total TCC bytes (~796 MB). Measured
//     structural ceiling for this random-line + stream mix: ~3.8 TB/s.
//     Probed and rejected: f16 table (fetch line-granular, unchanged),
//     i8 table (fill -55 MB but convert +160 MB), 2-users/thread
//     (conflict misses +57 MB), nt-hint L2 steering (no effect).

#define U_COUNT 1000000
#define K_NBR   10
#define D_DIM   32

typedef float f32x4 __attribute__((ext_vector_type(4)));

__global__ __launch_bounds__(256) void user_graph_gather_kernel(
    const float* __restrict__ features,   // [U, 32] f32  (reused -> cache)
    const int*   __restrict__ user_graph, // [U, 10] i32  (streamed)
    const float* __restrict__ user_matrix,// [U, 10] f32  (streamed)
    float* __restrict__ out)              // [U, 32] f32  (streamed)
{
    int t = blockIdx.x * blockDim.x + threadIdx.x;   // 8M threads
    int u = t >> 3;          // user id
    int r = t & 7;           // float4 slot within the 32-float row
    if (u >= U_COUNT) return;

    const int*   gu = user_graph + (long long)u * K_NBR;
    const float* wu = user_matrix + (long long)u * K_NBR;

    int   idx[K_NBR];
    float wk[K_NBR];
#pragma unroll
    for (int k = 0; k < K_NBR; ++k) {
        idx[k] = __builtin_nontemporal_load(gu + k);
        wk[k]  = __builtin_nontemporal_load(wu + k);
    }

    f32x4 acc = (f32x4)(0.f);
#pragma unroll
    for (int k = 0; k < K_NBR; ++k) {
        const f32x4* row = reinterpret_cast<const f32x4*>(
            features + (long long)idx[k] * D_DIM);
        f32x4 v = row[r];           // cached: feature table ~10x touch reuse
        acc += wk[k] * v;
    }

    f32x4* op = reinterpret_cast<f32x4*>(out) + ((long long)u * 8 + r);
    __builtin_nontemporal_store(acc, op);
}

extern "C" void kernel_launch(void* const* d_in, const int* in_sizes, int n_in,
                              void* d_out, int out_size, void* d_ws, size_t ws_size,
                              hipStream_t stream) {
    const float* features    = (const float*)d_in[0];  // 32M f32
    const int*   user_graph  = (const int*)d_in[1];    // 10M i32
    const float* user_matrix = (const float*)d_in[2];  // 10M f32
    float*       out         = (float*)d_out;          // 32M f32

    const int total_threads = U_COUNT * 8;        // 8,000,000
    const int block = 256;
    const int grid  = (total_threads + block - 1) / block;  // 31250

    user_graph_gather_kernel<<<grid, block, 0, stream>>>(
        features, user_graph, user_matrix, out);
}